// Round 6
// baseline (119.065 us; speedup 1.0000x reference)
//
#include <hip/hip_runtime.h>

// ExtractTsFeatures fused, f16-packed end-to-end: x (512,1024,32) fp32 -> out (512,32,30) fp32.
// R6 = R5 (48.7us: 2-level histogram selection) + latency pipelining + pass-2 dedupe:
//  - pass-1 histogram atomics issue BEFORE the moments/counts VALU block
//    (keys in separate regs), so atomic+conflict latency hides under ~700 cyc
//    of VALU; pass-2 atomics hide under the 5 red_sums.
//  - minmax + diffs (which use DS swizzle/bpermute) run BEFORE atomics1 so
//    they don't queue behind atomics in the in-order per-wave DS pipe.
//  - pass 2: ONE atomic per series per reg via representative-bucket select
//    (32 atomics/wave, was 96); exact under bucket collisions via per-series
//    dedupe (uniform) + piece-select at read time.
//  - launch_bounds(256,4): LDS caps residency at ~3.5 blocks/CU anyway;
//    allow 128 VGPR to guarantee no spill from the extra key regs.

typedef _Float16 h2 __attribute__((ext_vector_type(2)));
typedef unsigned int uint;
typedef unsigned long long u64;

#define KML0 0x0000000000000001ull   // lane 0 only
#define KML63 0x8000000000000000ull  // lane 63 only

__device__ __forceinline__ uint h2u(h2 v) { return __builtin_bit_cast(uint, v); }
__device__ __forceinline__ h2   u2h(uint v) { return __builtin_bit_cast(h2, v); }
__device__ __forceinline__ uint pkrtz(float a, float b) {
  return __builtin_bit_cast(uint, __builtin_amdgcn_cvt_pkrtz(a, b));
}
// pinned packed min/max (guarantee v_pk_*_f16)
__device__ __forceinline__ uint pmin(uint a, uint b) {
  uint r; asm("v_pk_min_f16 %0, %1, %2" : "=v"(r) : "v"(a), "v"(b)); return r;
}
__device__ __forceinline__ uint pmax(uint a, uint b) {
  uint r; asm("v_pk_max_f16 %0, %1, %2" : "=v"(r) : "v"(a), "v"(b)); return r;
}
// pinned per-lane select: lanes with mask-bit 1 take b, else a
__device__ __forceinline__ uint csel(uint a, uint b, u64 km) {
  uint r;
  asm("v_cndmask_b32 %0, %1, %2, %3" : "=v"(r) : "v"(a), "v"(b), "s"(km));
  return r;
}

// xor-exchange on packed u32: DPP masks 1,2,8 (VALU); swizzle 4,16.
template <int MASK>
__device__ __forceinline__ uint exu(uint x) {
  static_assert(MASK == 1 || MASK == 2 || MASK == 4 || MASK == 8 || MASK == 16,
                "bad mask");
  if constexpr (MASK == 1)  return (uint)__builtin_amdgcn_update_dpp(0, (int)x, 0xB1, 0xF, 0xF, true);
  if constexpr (MASK == 2)  return (uint)__builtin_amdgcn_update_dpp(0, (int)x, 0x4E, 0xF, 0xF, true);
  if constexpr (MASK == 8)  return (uint)__builtin_amdgcn_update_dpp(0, (int)x, 0x128, 0xF, 0xF, true);  // row_ror:8
  if constexpr (MASK == 4)  return (uint)__builtin_amdgcn_ds_swizzle((int)x, 0x101F);
  if constexpr (MASK == 16) return (uint)__builtin_amdgcn_ds_swizzle((int)x, 0x401F);
  return x;
}

__device__ __forceinline__ uint bpermu(int addr, uint x) {
  return (uint)__builtin_amdgcn_ds_bpermute(addr, (int)x);
}
__device__ __forceinline__ uint irdl(uint v, int l) {
  return (uint)__builtin_amdgcn_readlane((int)v, l);
}

// packed f16 DPP tree sum (both series); result uniform via readlane 63.
__device__ __forceinline__ uint red_sum_pk(uint v) {
#define RSTEP(C) { uint t = (uint)__builtin_amdgcn_update_dpp(0, (int)v, C, 0xF, 0xF, true); \
                   v = h2u(u2h(v) + u2h(t)); }
  RSTEP(0x111) RSTEP(0x112) RSTEP(0x114) RSTEP(0x118) RSTEP(0x142) RSTEP(0x143)
#undef RSTEP
  return irdl(v, 63);
}

// inclusive 64-lane add-scan, packed u32 (halves independent; cums <= 1024
// so no cross-half carry). Classic GCN DPP scan: 4x row_shr + 2x row_bcast.
__device__ __forceinline__ uint iscan_pk(uint v) {
#define SSTEP(C, RM) { uint t = (uint)__builtin_amdgcn_update_dpp(0, (int)v, C, RM, 0xF, true); \
                       v += t; }
  SSTEP(0x111, 0xF) SSTEP(0x112, 0xF) SSTEP(0x114, 0xF) SSTEP(0x118, 0xF)
  SSTEP(0x142, 0xA) SSTEP(0x143, 0xC)
#undef SSTEP
  return v;
}

// load 4 bins/lane from a 256-bin packed histogram; in-lane exclusive
// prefixes + wave scan pieces.
__device__ __forceinline__ void histpieces(const uint* base, int lane,
                                           uint& e1, uint& e2, uint& e3,
                                           uint& S, uint& cumb) {
  uint4 bv = *(const uint4*)(base + (lane << 2));
  e1 = bv.x; e2 = e1 + bv.y; e3 = e2 + bv.z;
  uint tot = e3 + bv.w;
  S = iscan_pk(tot);
  cumb = S - tot;
}

// find bin containing 0-based rank R for series half sh (0 or 16).
// bucket = bin index (0..255), resid = rank within that bin.
__device__ __forceinline__ void rankfind(uint R, int sh, uint e1, uint e2,
                                         uint e3, uint S, uint cumb,
                                         uint& bucket, uint& resid) {
  uint Ss = (S >> sh) & 0xFFFFu;
  u64 m = __ballot(Ss > R);
  int L = (int)__builtin_ctzll(m);
  uint cb = (irdl(cumb, L) >> sh) & 0xFFFFu;
  uint f1 = (irdl(e1, L) >> sh) & 0xFFFFu;
  uint f2 = (irdl(e2, L) >> sh) & 0xFFFFu;
  uint f3 = (irdl(e3, L) >> sh) & 0xFFFFu;
  uint r0 = R - cb;
  uint j = (uint)(r0 >= f1) + (uint)(r0 >= f2) + (uint)(r0 >= f3);
  uint ej = (j == 0) ? 0u : (j == 1) ? f1 : (j == 2) ? f2 : f3;
  bucket = ((uint)L << 2) + j;
  resid = r0 - ej;
}

__global__ __launch_bounds__(256, 4) void feat_fused(const float* __restrict__ x,
                                                     float* __restrict__ out) {
  __shared__ __align__(16) uint sm[4 * 1024];  // 4 packed rows x 1024 = 16 KiB
  __shared__ uint rawstash[4 * 20];            // per-wave raw packed stats
  __shared__ float stash[8 * 30];              // per-block output stage (960 B)
  const int tid  = threadIdx.x;
  const int lane = tid & 63;
  const int wv   = tid >> 6;
  const int g    = blockIdx.x;
  const int b  = ((g & 7) << 6) + (g >> 5);   // XCD swizzle: siblings share L2
  const int f8 = (g >> 3) & 3;

  // ---- stage 8 series as 4 packed f16 rows ----
  const float4* xv = (const float4*)x;
  const int fq = tid & 1, t0 = tid >> 1;
  const size_t base4 = (size_t)b * 8192 + (size_t)((f8 << 1) + fq);
#pragma unroll
  for (int it = 0; it < 8; ++it) {
    int t = t0 + (it << 7);
    float4 v = xv[base4 + (size_t)t * 8];
    sm[((fq << 1) + 0) * 1024 + t] = pkrtz(v.x, v.y);
    sm[((fq << 1) + 1) * 1024 + t] = pkrtz(v.z, v.w);
  }
  __syncthreads();

  // packed series pair: lo = f8*8 + 2*wv, hi = +1
  uint p[16];
  {
    const uint* src = sm + (wv << 10);
#pragma unroll
    for (int q = 0; q < 4; ++q) {
      uint4 v = *(const uint4*)(src + (q << 8) + (lane << 2));
      p[q * 4 + 0] = v.x; p[q * 4 + 1] = v.y;
      p[q * 4 + 2] = v.z; p[q * 4 + 3] = v.w;
    }
  }

  const int addr_nx = ((lane + 1) & 63) << 2;
  const int addr63  = (lane ^ 63) << 2;
  const bool is63 = (lane == 63);
  uint* hb = sm + (wv << 10);   // wave-private 1024-word histogram region

  // ---- DS-using phases FIRST (before atomics enter the in-order DS pipe) ---
  // f16 min/max on original values (packed, full-wave reduction)
  uint mnv = p[0], mxv = p[0];
#pragma unroll
  for (int r = 1; r < 16; ++r) { mnv = pmin(mnv, p[r]); mxv = pmax(mxv, p[r]); }
  mnv = pmin(mnv, exu<1>(mnv));  mxv = pmax(mxv, exu<1>(mxv));
  mnv = pmin(mnv, exu<2>(mnv));  mxv = pmax(mxv, exu<2>(mxv));
  mnv = pmin(mnv, exu<4>(mnv));  mxv = pmax(mxv, exu<4>(mxv));
  mnv = pmin(mnv, exu<8>(mnv));  mxv = pmax(mxv, exu<8>(mxv));
  mnv = pmin(mnv, exu<16>(mnv)); mxv = pmax(mxv, exu<16>(mxv));
  mnv = pmin(mnv, bpermu(addr63, mnv));   // cross 32-lane halves
  mxv = pmax(mxv, bpermu(addr63, mxv));
  uint mnp = irdl(mnv, 0), mxp = irdl(mxv, 0);

  // diffs d_t = x[t]-x[t+1], t in [1,1022], packed (bpermute-based)
  uint j1 = irdl(p[4], 0), j2 = irdl(p[8], 0), j3 = irdl(p[12], 0);
  h2 sadh = {0, 0}, sddh = {0, 0};
#pragma unroll
  for (int q = 0; q < 4; ++q) {
    uint nv = bpermu(addr_nx, p[q * 4]);
    if (q == 0) nv = is63 ? j1 : nv;
    if (q == 1) nv = is63 ? j2 : nv;
    if (q == 2) nv = is63 ? j3 : nv;
#pragma unroll
    for (int i = 0; i < 4; ++i) {
      uint xn = (i < 3) ? p[q * 4 + i + 1] : nv;
      uint dvu = h2u(u2h(p[q * 4 + i]) - u2h(xn));
      if (q == 0 && i == 0) dvu = csel(dvu, 0u, KML0);   // t=0 excluded
      if (q == 3 && i == 3) dvu = csel(dvu, 0u, KML63);  // t=1023 excluded
      h2 dv = u2h(dvu);
      sadh += u2h(dvu & 0x7FFF7FFFu);
      sddh += dv * dv;
    }
  }
  uint x1p = irdl(p[1], 0), x1023p = irdl(p[15], 63);
  uint SDp = irdl(h2u(u2h(x1p) - u2h(x1023p)), 0);

  // tb values at t = 0, 256, 512, 767, 1023 (packed, uniform)
  uint tb0p = irdl(p[0], 0);
  uint tb1p = irdl(p[4], 0);
  uint tb2p = irdl(p[8], 0);
  uint tb3p = irdl(p[11], 63);
  uint tb4p = irdl(p[15], 63);

  // ---- zero whole histogram row + order-isomorphic keys + pass-1 atomics ---
  {
    uint4 zz; zz.x = 0u; zz.y = 0u; zz.z = 0u; zz.w = 0u;
#pragma unroll
    for (int z = 0; z < 4; ++z) *(uint4*)(hb + (z << 8) + (lane << 2)) = zz;
  }
  uint k[16];
#pragma unroll
  for (int r = 0; r < 16; ++r) {
    uint sg = (p[r] >> 15) & 0x10001u;
    k[r] = p[r] ^ (sg * 0x7FFFu) ^ 0x80008000u;
  }
  __asm__ volatile("" ::: "memory");
#pragma unroll
  for (int r = 0; r < 16; ++r) {
    atomicAdd(hb + ((k[r] >> 8) & 0xFFu), 1u);
    atomicAdd(hb + (k[r] >> 24), 0x10000u);
  }
  __asm__ volatile("" ::: "memory");

  // ---- pure-VALU stats run while pass-1 atomics settle ----
  h2 s1h = {0, 0}, s2h = {0, 0}, s3h = {0, 0}, s4h = {0, 0};
#pragma unroll
  for (int r = 0; r < 16; ++r) {
    h2 v = u2h(p[r]);
    h2 v2 = v * v;
    s1h += v;
    s2h += v2;
    s3h += v2 * v;
    s4h += v2 * v2;
  }
  uint s1r = red_sum_pk(h2u(s1h));
  const _Float16 inv1024 = (_Float16)(1.0f / 1024.0f);
  h2 invv = {inv1024, inv1024};
  uint meanp = irdl(h2u(u2h(s1r) * invv), 0);

  // counts: 1 v_cmp_gt_f16 per series per reg (ballot/popc are scalar-side)
  const uint tb0hh = tb0p >> 16, tb1hh = tb1p >> 16, tb2hh = tb2p >> 16;
  const uint tb3hh = tb3p >> 16, tb4hh = tb4p >> 16, meanhh = meanp >> 16;
  int cposA = 0, cposB = 0, cmA = 0, cmB = 0;
  int c0A = 0, c0B = 0, c1A = 0, c1B = 0, c2A = 0, c2B = 0;
  int c3A = 0, c3B = 0, c4A = 0, c4B = 0;
#pragma unroll
  for (int r = 0; r < 16; ++r) {
    _Float16 a = u2h(p[r]).x;
    _Float16 bb = u2h(p[r] >> 16).x;
    cposA += __popcll(__ballot(a > (_Float16)0));
    cposB += __popcll(__ballot(bb > (_Float16)0));
    cmA += __popcll(__ballot(a > u2h(meanp).x));
    cmB += __popcll(__ballot(bb > u2h(meanhh).x));
    c0A += __popcll(__ballot(a > u2h(tb0p).x));
    c0B += __popcll(__ballot(bb > u2h(tb0hh).x));
    c1A += __popcll(__ballot(a > u2h(tb1p).x));
    c1B += __popcll(__ballot(bb > u2h(tb1hh).x));
    c2A += __popcll(__ballot(a > u2h(tb2p).x));
    c2B += __popcll(__ballot(bb > u2h(tb2hh).x));
    c3A += __popcll(__ballot(a > u2h(tb3p).x));
    c3B += __popcll(__ballot(bb > u2h(tb3hh).x));
    c4A += __popcll(__ballot(a > u2h(tb4p).x));
    c4B += __popcll(__ballot(bb > u2h(tb4hh).x));
  }

  // ---- read pass-1 histogram, find rank buckets ----
  uint e1, e2, e3, S, cumb;
  histpieces(hb, lane, e1, e2, e3, S, cumb);
  uint b1[2][3], r1[2][3];
#pragma unroll
  for (int s = 0; s < 2; ++s) {
#pragma unroll
    for (int kk = 0; kk < 3; ++kk) {
      const uint R = (kk == 0) ? 256u : (kk == 1) ? 512u : 767u;
      rankfind(R, s << 4, e1, e2, e3, S, cumb, b1[s][kk], r1[s][kk]);
    }
  }

  // dedupe per series: representative buckets & read slots (uniform scalars)
  uint rep[2][3]; int slt[2][3];
#pragma unroll
  for (int s = 0; s < 2; ++s) {
    uint B0 = b1[s][0], B1 = b1[s][1], B2 = b1[s][2];
    slt[s][0] = 0; rep[s][0] = B0;
    bool d10 = (B1 == B0);
    slt[s][1] = d10 ? 0 : 1;
    rep[s][1] = d10 ? 0xFFFFu : B1;
    int s2s = (B2 == B0) ? 0 : ((B2 == B1) ? slt[s][1] : 2);
    slt[s][2] = s2s;
    rep[s][2] = (s2s == 2) ? B2 : 0xFFFFu;
  }

  // ---- pass-2 atomics: ONE per series per reg (trash = per-lane slot in
  //      the now-dead pass-1 bin area) ----
  __asm__ volatile("" ::: "memory");
  const uint trash = (uint)lane;
#pragma unroll
  for (int r = 0; r < 16; ++r) {
    uint loA = k[r] & 0xFFu,         hiA = (k[r] >> 8) & 0xFFu;
    uint loB = (k[r] >> 16) & 0xFFu, hiB = k[r] >> 24;
    uint ia = trash;
    ia = (hiA == rep[0][0]) ? (256u + loA) : ia;
    ia = (hiA == rep[0][1]) ? (512u + loA) : ia;
    ia = (hiA == rep[0][2]) ? (768u + loA) : ia;
    atomicAdd(hb + ia, 1u);
    uint ib = trash;
    ib = (hiB == rep[1][0]) ? (256u + loB) : ib;
    ib = (hiB == rep[1][1]) ? (512u + loB) : ib;
    ib = (hiB == rep[1][2]) ? (768u + loB) : ib;
    atomicAdd(hb + ib, 0x10000u);
  }
  __asm__ volatile("" ::: "memory");

  // ---- red_sums + rawstash write run while pass-2 atomics settle ----
  uint s2r = red_sum_pk(h2u(s2h));
  uint s3r = red_sum_pk(h2u(s3h));
  uint s4r = red_sum_pk(h2u(s4h));
  uint sadr = red_sum_pk(h2u(sadh));
  uint sddr = red_sum_pk(h2u(sddh));

  if (lane == 0) {
    uint* rs = rawstash + wv * 20;
    rs[0] = meanp; rs[1] = s2r; rs[2] = s3r; rs[3] = s4r;
    rs[4] = sadr;  rs[5] = sddr; rs[6] = SDp;
    rs[7] = tb0p;  rs[8] = tb1p; rs[9] = tb2p; rs[10] = tb3p; rs[11] = tb4p;
    rs[12] = (uint)(cposA | (cposB << 16));
    rs[13] = (uint)(cmA | (cmB << 16));
    rs[14] = (uint)(c0A | (c0B << 16));
    rs[15] = (uint)(c1A | (c1B << 16));
    rs[16] = (uint)(c2A | (c2B << 16));
    rs[17] = (uint)(c3A | (c3B << 16));
    rs[18] = (uint)(c4A | (c4B << 16));
  }

  // ---- read pass-2 histograms, resolve low bytes ----
  uint F1[3], F2[3], F3[3], SS2[3], CB2[3];
#pragma unroll
  for (int j = 0; j < 3; ++j)
    histpieces(hb + 256 + (j << 8), lane, F1[j], F2[j], F3[j], SS2[j], CB2[j]);
  float qv[2][3];
#pragma unroll
  for (int kk = 0; kk < 3; ++kk) {
#pragma unroll
    for (int s = 0; s < 2; ++s) {
      int m = slt[s][kk];
      uint f1 = (m == 0) ? F1[0] : (m == 1) ? F1[1] : F1[2];
      uint f2 = (m == 0) ? F2[0] : (m == 1) ? F2[1] : F2[2];
      uint f3 = (m == 0) ? F3[0] : (m == 1) ? F3[1] : F3[2];
      uint Sx = (m == 0) ? SS2[0] : (m == 1) ? SS2[1] : SS2[2];
      uint cx = (m == 0) ? CB2[0] : (m == 1) ? CB2[1] : CB2[2];
      uint lob, dummy;
      rankfind(r1[s][kk], s << 4, f1, f2, f3, Sx, cx, lob, dummy);
      uint key = (b1[s][kk] << 8) | lob;
      uint h = (key & 0x8000u) ? (key & 0x7FFFu) : (~key & 0xFFFFu);
      qv[s][kk] = (float)u2h(h).x;
    }
  }

  // ---- patch sort-derived outputs into the stash (per wave, lane0) ----
  if (lane == 0) {
#pragma unroll
    for (int s = 0; s < 2; ++s) {
      int sh = s << 4;
      float mnf = (float)u2h(mnp >> sh).x;
      float mxf = (float)u2h(mxp >> sh).x;
      float* o = stash + ((wv << 1) + s) * 30;
      o[1]  = mnf;
      o[2]  = mxf;
      o[11] = qv[s][0];
      o[12] = qv[s][1];
      o[13] = qv[s][2];
      o[20] = fmaxf(fabsf(mnf), fabsf(mxf));
    }
  }
  __syncthreads();

  // ---- block-level epilogue: tid 0..7 -> one series each ----
  if (tid < 8) {
    const uint* rs = rawstash + (tid >> 1) * 20;
    const int sh = (tid & 1) << 4;
    float mean = (float)u2h(rs[0] >> sh).x;
    float s2   = (float)u2h(rs[1] >> sh).x;
    float s3   = (float)u2h(rs[2] >> sh).x;
    float s4   = (float)u2h(rs[3] >> sh).x;
    float sad  = (float)u2h(rs[4] >> sh).x;
    float sdd  = (float)u2h(rs[5] >> sh).x;
    float SD   = (float)u2h(rs[6] >> sh).x;
    float tb0  = (float)u2h(rs[7] >> sh).x;
    float tb1  = (float)u2h(rs[8] >> sh).x;
    float tb2  = (float)u2h(rs[9] >> sh).x;
    float tb3  = (float)u2h(rs[10] >> sh).x;
    float tb4  = (float)u2h(rs[11] >> sh).x;
    float fcpos = (float)((rs[12] >> sh) & 0xFFFF);
    float fcm   = (float)((rs[13] >> sh) & 0xFFFF);
    float fc0   = (float)((rs[14] >> sh) & 0xFFFF);
    float fc1   = (float)((rs[15] >> sh) & 0xFFFF);
    float fc2   = (float)((rs[16] >> sh) & 0xFFFF);
    float fc3   = (float)((rs[17] >> sh) & 0xFFFF);
    float fc4   = (float)((rs[18] >> sh) & 0xFFFF);

    float ex2 = s2 * (1.0f / 1024.0f);
    float rms = __builtin_amdgcn_sqrtf(fmaxf(ex2, 0.f));
    float var = fmaxf(ex2 - mean * mean, 0.f);
    float stdv = __builtin_amdgcn_sqrtf(var);
    float m2 = mean * mean;
    float m3c = s3 - 3.f * mean * s2 + 2048.f * m2 * mean;
    const float coef3 = (float)(1024.0 / (1023.0 * 1022.0));
    float den3 = stdv * stdv * stdv;
    float skew = (den3 > 0.f) ? coef3 * m3c * __builtin_amdgcn_rcpf(den3) : 0.f;
    float k4c = s4 - 4.f * mean * s3 + 6.f * m2 * s2 - 3072.f * m2 * m2;
    float s2c = s2 - 1024.f * m2;
    float k22 = s2c * s2c;
    const float alpha = (float)(1024.0 * 1025.0 * 1023.0 / (1022.0 * 1021.0));
    const float rightc = (float)(3.0 * 1023.0 * 1023.0 / (1022.0 * 1021.0));
    float kurt = (k22 > 0.f) ? alpha * k4c * __builtin_amdgcn_rcpf(k22) - rightc
                             : -rightc;

    float* o = stash + tid * 30;
    o[0] = mean;  o[3] = rms;  o[4] = var;  o[5] = stdv;
    o[6] = skew;  o[7] = kurt;
    o[8] = SD * (1.0f / 1022.0f);
    o[9] = SD;
    o[10] = sad * (1.0f / 1022.0f);
    o[14] = tb0;  o[15] = tb1; o[16] = tb2; o[17] = tb3; o[18] = tb4;
    o[19] = s2;
    o[21] = sad;
    o[22] = __builtin_amdgcn_sqrtf(fmaxf(sdd, 0.f));
    o[23] = fcpos; o[24] = fcm;
    o[25] = fc0;   o[26] = fc1; o[27] = fc2; o[28] = fc3; o[29] = fc4;
  }
  __syncthreads();

  // ---- coalesced block output: 8 rows x 30 floats = 960 B contiguous ----
  if (tid < 240) {
    size_t base = ((size_t)((b << 5) + (f8 << 3))) * 30;
    out[base + tid] = stash[tid];
  }
}

extern "C" void kernel_launch(void* const* d_in, const int* in_sizes, int n_in,
                              void* d_out, int out_size, void* d_ws, size_t ws_size,
                              hipStream_t stream) {
  const float* x = (const float*)d_in[0];
  float* out = (float*)d_out;
  hipLaunchKernelGGL(feat_fused, dim3(2048), dim3(256), 0, stream, x, out);
}

// Round 7
// 117.645 us; speedup vs baseline: 1.0121x; 1.0121x over previous
//
#include <hip/hip_runtime.h>

// ExtractTsFeatures fused, f16-packed end-to-end: x (512,1024,32) fp32 -> out (512,32,30) fp32.
// R7 = R5 EXACTLY (48.7us dispatch / 115.6 graded: 2-level histogram selection,
// proven phase order) + ONE isolated delta: pass-2 dedupe. Pass-2 issues ONE
// atomic per series per reg (32/wave, was 96) via representative-bucket select;
// exact under bucket collisions via per-series dedupe (wave-uniform SALU on
// ballot/readlane results) + piece-select at read time. R6 proved the dedupe
// logic correct; R6's regression is attributed to its phase REORDER (VALUBusy
// 55->32% with same inst stream), which is fully reverted here.

typedef _Float16 h2 __attribute__((ext_vector_type(2)));
typedef unsigned int uint;
typedef unsigned long long u64;

#define KML0 0x0000000000000001ull   // lane 0 only
#define KML63 0x8000000000000000ull  // lane 63 only

__device__ __forceinline__ uint h2u(h2 v) { return __builtin_bit_cast(uint, v); }
__device__ __forceinline__ h2   u2h(uint v) { return __builtin_bit_cast(h2, v); }
__device__ __forceinline__ uint pkrtz(float a, float b) {
  return __builtin_bit_cast(uint, __builtin_amdgcn_cvt_pkrtz(a, b));
}
// pinned packed min/max (guarantee v_pk_*_f16)
__device__ __forceinline__ uint pmin(uint a, uint b) {
  uint r; asm("v_pk_min_f16 %0, %1, %2" : "=v"(r) : "v"(a), "v"(b)); return r;
}
__device__ __forceinline__ uint pmax(uint a, uint b) {
  uint r; asm("v_pk_max_f16 %0, %1, %2" : "=v"(r) : "v"(a), "v"(b)); return r;
}
// pinned per-lane select: lanes with mask-bit 1 take b, else a
__device__ __forceinline__ uint csel(uint a, uint b, u64 km) {
  uint r;
  asm("v_cndmask_b32 %0, %1, %2, %3" : "=v"(r) : "v"(a), "v"(b), "s"(km));
  return r;
}

// xor-exchange on packed u32: DPP masks 1,2,8 (VALU); swizzle 4,16.
template <int MASK>
__device__ __forceinline__ uint exu(uint x) {
  static_assert(MASK == 1 || MASK == 2 || MASK == 4 || MASK == 8 || MASK == 16,
                "bad mask");
  if constexpr (MASK == 1)  return (uint)__builtin_amdgcn_update_dpp(0, (int)x, 0xB1, 0xF, 0xF, true);
  if constexpr (MASK == 2)  return (uint)__builtin_amdgcn_update_dpp(0, (int)x, 0x4E, 0xF, 0xF, true);
  if constexpr (MASK == 8)  return (uint)__builtin_amdgcn_update_dpp(0, (int)x, 0x128, 0xF, 0xF, true);  // row_ror:8
  if constexpr (MASK == 4)  return (uint)__builtin_amdgcn_ds_swizzle((int)x, 0x101F);
  if constexpr (MASK == 16) return (uint)__builtin_amdgcn_ds_swizzle((int)x, 0x401F);
  return x;
}

__device__ __forceinline__ uint bpermu(int addr, uint x) {
  return (uint)__builtin_amdgcn_ds_bpermute(addr, (int)x);
}
__device__ __forceinline__ uint irdl(uint v, int l) {
  return (uint)__builtin_amdgcn_readlane((int)v, l);
}

// packed f16 DPP tree sum (both series); result uniform via readlane 63.
__device__ __forceinline__ uint red_sum_pk(uint v) {
#define RSTEP(C) { uint t = (uint)__builtin_amdgcn_update_dpp(0, (int)v, C, 0xF, 0xF, true); \
                   v = h2u(u2h(v) + u2h(t)); }
  RSTEP(0x111) RSTEP(0x112) RSTEP(0x114) RSTEP(0x118) RSTEP(0x142) RSTEP(0x143)
#undef RSTEP
  return irdl(v, 63);
}

// inclusive 64-lane add-scan, packed u32 (halves independent; cums <= 1024
// so no cross-half carry). Classic GCN DPP scan: 4x row_shr + 2x row_bcast.
__device__ __forceinline__ uint iscan_pk(uint v) {
#define SSTEP(C, RM) { uint t = (uint)__builtin_amdgcn_update_dpp(0, (int)v, C, RM, 0xF, true); \
                       v += t; }
  SSTEP(0x111, 0xF) SSTEP(0x112, 0xF) SSTEP(0x114, 0xF) SSTEP(0x118, 0xF)
  SSTEP(0x142, 0xA) SSTEP(0x143, 0xC)
#undef SSTEP
  return v;
}

// load 4 bins/lane from a 256-bin packed histogram; in-lane exclusive
// prefixes + wave scan pieces.
__device__ __forceinline__ void histpieces(const uint* base, int lane,
                                           uint& e1, uint& e2, uint& e3,
                                           uint& S, uint& cumb) {
  uint4 bv = *(const uint4*)(base + (lane << 2));
  e1 = bv.x; e2 = e1 + bv.y; e3 = e2 + bv.z;
  uint tot = e3 + bv.w;
  S = iscan_pk(tot);
  cumb = S - tot;
}

// find bin containing 0-based rank R for series half sh (0 or 16).
// bucket = bin index (0..255), resid = rank within that bin.
__device__ __forceinline__ void rankfind(uint R, int sh, uint e1, uint e2,
                                         uint e3, uint S, uint cumb,
                                         uint& bucket, uint& resid) {
  uint Ss = (S >> sh) & 0xFFFFu;
  u64 m = __ballot(Ss > R);
  int L = (int)__builtin_ctzll(m);
  uint cb = (irdl(cumb, L) >> sh) & 0xFFFFu;
  uint f1 = (irdl(e1, L) >> sh) & 0xFFFFu;
  uint f2 = (irdl(e2, L) >> sh) & 0xFFFFu;
  uint f3 = (irdl(e3, L) >> sh) & 0xFFFFu;
  uint r0 = R - cb;
  uint j = (uint)(r0 >= f1) + (uint)(r0 >= f2) + (uint)(r0 >= f3);
  uint ej = (j == 0) ? 0u : (j == 1) ? f1 : (j == 2) ? f2 : f3;
  bucket = ((uint)L << 2) + j;
  resid = r0 - ej;
}

__global__ __launch_bounds__(256, 6) void feat_fused(const float* __restrict__ x,
                                                     float* __restrict__ out) {
  __shared__ __align__(16) uint sm[4 * 1024];  // 4 packed rows x 1024 = 16 KiB
  __shared__ uint rawstash[4 * 20];            // per-wave raw packed stats
  __shared__ float stash[8 * 30];              // per-block output stage (960 B)
  const int tid  = threadIdx.x;
  const int lane = tid & 63;
  const int wv   = tid >> 6;
  const int g    = blockIdx.x;
  const int b  = ((g & 7) << 6) + (g >> 5);   // XCD swizzle: siblings share L2
  const int f8 = (g >> 3) & 3;

  // ---- stage 8 series as 4 packed f16 rows ----
  const float4* xv = (const float4*)x;
  const int fq = tid & 1, t0 = tid >> 1;
  const size_t base4 = (size_t)b * 8192 + (size_t)((f8 << 1) + fq);
#pragma unroll
  for (int it = 0; it < 8; ++it) {
    int t = t0 + (it << 7);
    float4 v = xv[base4 + (size_t)t * 8];
    sm[((fq << 1) + 0) * 1024 + t] = pkrtz(v.x, v.y);
    sm[((fq << 1) + 1) * 1024 + t] = pkrtz(v.z, v.w);
  }
  __syncthreads();

  // packed series pair: lo = f8*8 + 2*wv, hi = +1
  uint p[16];
  {
    const uint* src = sm + (wv << 10);
#pragma unroll
    for (int q = 0; q < 4; ++q) {
      uint4 v = *(const uint4*)(src + (q << 8) + (lane << 2));
      p[q * 4 + 0] = v.x; p[q * 4 + 1] = v.y;
      p[q * 4 + 2] = v.z; p[q * 4 + 3] = v.w;
    }
  }

  const int addr_nx = ((lane + 1) & 63) << 2;
  const int addr63  = (lane ^ 63) << 2;
  const bool is63 = (lane == 63);

  // ============== packed per-series stats (both series at once) ===========
  // tb values at t = 0, 256, 512, 767, 1023 (packed, uniform)
  uint tb0p = irdl(p[0], 0);
  uint tb1p = irdl(p[4], 0);
  uint tb2p = irdl(p[8], 0);
  uint tb3p = irdl(p[11], 63);
  uint tb4p = irdl(p[15], 63);

  // raw moments, packed f16
  h2 s1h = {0, 0}, s2h = {0, 0}, s3h = {0, 0}, s4h = {0, 0};
#pragma unroll
  for (int r = 0; r < 16; ++r) {
    h2 v = u2h(p[r]);
    h2 v2 = v * v;
    s1h += v;
    s2h += v2;
    s3h += v2 * v;
    s4h += v2 * v2;
  }
  uint s1r = red_sum_pk(h2u(s1h));
  const _Float16 inv1024 = (_Float16)(1.0f / 1024.0f);
  h2 invv = {inv1024, inv1024};
  uint meanp = irdl(h2u(u2h(s1r) * invv), 0);

  // counts: 1 v_cmp_gt_f16 per series per reg; hi half via one lshr per reg
  const uint tb0hh = tb0p >> 16, tb1hh = tb1p >> 16, tb2hh = tb2p >> 16;
  const uint tb3hh = tb3p >> 16, tb4hh = tb4p >> 16, meanhh = meanp >> 16;
  int cposA = 0, cposB = 0, cmA = 0, cmB = 0;
  int c0A = 0, c0B = 0, c1A = 0, c1B = 0, c2A = 0, c2B = 0;
  int c3A = 0, c3B = 0, c4A = 0, c4B = 0;
#pragma unroll
  for (int r = 0; r < 16; ++r) {
    _Float16 a = u2h(p[r]).x;
    _Float16 bb = u2h(p[r] >> 16).x;
    cposA += __popcll(__ballot(a > (_Float16)0));
    cposB += __popcll(__ballot(bb > (_Float16)0));
    cmA += __popcll(__ballot(a > u2h(meanp).x));
    cmB += __popcll(__ballot(bb > u2h(meanhh).x));
    c0A += __popcll(__ballot(a > u2h(tb0p).x));
    c0B += __popcll(__ballot(bb > u2h(tb0hh).x));
    c1A += __popcll(__ballot(a > u2h(tb1p).x));
    c1B += __popcll(__ballot(bb > u2h(tb1hh).x));
    c2A += __popcll(__ballot(a > u2h(tb2p).x));
    c2B += __popcll(__ballot(bb > u2h(tb2hh).x));
    c3A += __popcll(__ballot(a > u2h(tb3p).x));
    c3B += __popcll(__ballot(bb > u2h(tb3hh).x));
    c4A += __popcll(__ballot(a > u2h(tb4p).x));
    c4B += __popcll(__ballot(bb > u2h(tb4hh).x));
  }

  // diffs d_t = x[t]-x[t+1], t in [1,1022], packed; sum telescopes.
  uint j1 = irdl(p[4], 0), j2 = irdl(p[8], 0), j3 = irdl(p[12], 0);
  h2 sadh = {0, 0}, sddh = {0, 0};
#pragma unroll
  for (int q = 0; q < 4; ++q) {
    uint nv = bpermu(addr_nx, p[q * 4]);
    if (q == 0) nv = is63 ? j1 : nv;
    if (q == 1) nv = is63 ? j2 : nv;
    if (q == 2) nv = is63 ? j3 : nv;
#pragma unroll
    for (int i = 0; i < 4; ++i) {
      uint xn = (i < 3) ? p[q * 4 + i + 1] : nv;
      uint dvu = h2u(u2h(p[q * 4 + i]) - u2h(xn));
      if (q == 0 && i == 0) dvu = csel(dvu, 0u, KML0);   // t=0 excluded
      if (q == 3 && i == 3) dvu = csel(dvu, 0u, KML63);  // t=1023 excluded
      h2 dv = u2h(dvu);
      sadh += u2h(dvu & 0x7FFF7FFFu);
      sddh += dv * dv;
    }
  }
  uint s2r = red_sum_pk(h2u(s2h));
  uint s3r = red_sum_pk(h2u(s3h));
  uint s4r = red_sum_pk(h2u(s4h));
  uint sadr = red_sum_pk(h2u(sadh));
  uint sddr = red_sum_pk(h2u(sddh));
  uint x1p = irdl(p[1], 0), x1023p = irdl(p[15], 63);
  uint SDp = irdl(h2u(u2h(x1p) - u2h(x1023p)), 0);

  if (lane == 0) {
    uint* rs = rawstash + wv * 20;
    rs[0] = meanp; rs[1] = s2r; rs[2] = s3r; rs[3] = s4r;
    rs[4] = sadr;  rs[5] = sddr; rs[6] = SDp;
    rs[7] = tb0p;  rs[8] = tb1p; rs[9] = tb2p; rs[10] = tb3p; rs[11] = tb4p;
    rs[12] = (uint)(cposA | (cposB << 16));
    rs[13] = (uint)(cmA | (cmB << 16));
    rs[14] = (uint)(c0A | (c0B << 16));
    rs[15] = (uint)(c1A | (c1B << 16));
    rs[16] = (uint)(c2A | (c2B << 16));
    rs[17] = (uint)(c3A | (c3B << 16));
    rs[18] = (uint)(c4A | (c4B << 16));
  }

  // ======== exact order statistics via 2-level LDS histogram ==============
  // wave-private 1024-word region = the staging row this wave alone consumed.
  uint* hb = sm + (wv << 10);

  // -- f16 min/max on original values (packed, full-wave reduction) --
  uint mnv = p[0], mxv = p[0];
#pragma unroll
  for (int r = 1; r < 16; ++r) { mnv = pmin(mnv, p[r]); mxv = pmax(mxv, p[r]); }
  mnv = pmin(mnv, exu<1>(mnv));  mxv = pmax(mxv, exu<1>(mxv));
  mnv = pmin(mnv, exu<2>(mnv));  mxv = pmax(mxv, exu<2>(mxv));
  mnv = pmin(mnv, exu<4>(mnv));  mxv = pmax(mxv, exu<4>(mxv));
  mnv = pmin(mnv, exu<8>(mnv));  mxv = pmax(mxv, exu<8>(mxv));
  mnv = pmin(mnv, exu<16>(mnv)); mxv = pmax(mxv, exu<16>(mxv));
  mnv = pmin(mnv, bpermu(addr63, mnv));   // cross 32-lane halves
  mxv = pmax(mxv, bpermu(addr63, mxv));
  uint mnp = irdl(mnv, 0), mxp = irdl(mxv, 0);

  // -- transform to order-isomorphic u16 keys, in place --
  // key = sign ? ~h : (h | 0x8000), per 16-bit half.
#pragma unroll
  for (int r = 0; r < 16; ++r) {
    uint sg = (p[r] >> 15) & 0x10001u;
    p[r] = p[r] ^ (sg * 0x7FFFu) ^ 0x80008000u;
  }

  // -- pass 1: 256-bin histogram of high key byte (A in lo16, B in hi16) --
  {
    uint4 zz; zz.x = 0u; zz.y = 0u; zz.z = 0u; zz.w = 0u;
    *(uint4*)(hb + (lane << 2)) = zz;
  }
  __asm__ volatile("" ::: "memory");
#pragma unroll
  for (int r = 0; r < 16; ++r) {
    atomicAdd(hb + ((p[r] >> 8) & 0xFFu), 1u);
    atomicAdd(hb + (p[r] >> 24), 0x10000u);
  }
  __asm__ volatile("" ::: "memory");
  uint e1, e2, e3, S, cumb;
  histpieces(hb, lane, e1, e2, e3, S, cumb);
  uint b1[2][3], r1[2][3];
#pragma unroll
  for (int s = 0; s < 2; ++s) {
#pragma unroll
    for (int k = 0; k < 3; ++k) {
      const uint R = (k == 0) ? 256u : (k == 1) ? 512u : 767u;
      rankfind(R, s << 4, e1, e2, e3, S, cumb, b1[s][k], r1[s][k]);
    }
  }

  // -- dedupe per series: representative buckets & read slots (uniform SALU) --
  uint rep[2][3]; int slt[2][3];
#pragma unroll
  for (int s = 0; s < 2; ++s) {
    uint B0 = b1[s][0], B1 = b1[s][1], B2 = b1[s][2];
    slt[s][0] = 0; rep[s][0] = B0;
    bool d10 = (B1 == B0);
    slt[s][1] = d10 ? 0 : 1;
    rep[s][1] = d10 ? 0xFFFFu : B1;
    int s2s = (B2 == B0) ? 0 : ((B2 == B1) ? slt[s][1] : 2);
    slt[s][2] = s2s;
    rep[s][2] = (s2s == 2) ? B2 : 0xFFFFu;
  }

  // -- pass 2: per-slot 256-bin histograms of low key byte; ONE atomic per
  //    series per reg (trash = per-lane slot in dead pass-1 bin area) --
  {
    uint4 zz; zz.x = 0u; zz.y = 0u; zz.z = 0u; zz.w = 0u;
#pragma unroll
    for (int z = 0; z < 3; ++z)
      *(uint4*)(hb + 256 + (z << 8) + (lane << 2)) = zz;
  }
  __asm__ volatile("" ::: "memory");
  const uint trash = (uint)lane;   // pass-1 bins are dead; per-lane slots
#pragma unroll
  for (int r = 0; r < 16; ++r) {
    uint loA = p[r] & 0xFFu,         hiA = (p[r] >> 8) & 0xFFu;
    uint loB = (p[r] >> 16) & 0xFFu, hiB = p[r] >> 24;
    uint ia = trash;
    ia = (hiA == rep[0][0]) ? (256u + loA) : ia;
    ia = (hiA == rep[0][1]) ? (512u + loA) : ia;
    ia = (hiA == rep[0][2]) ? (768u + loA) : ia;
    atomicAdd(hb + ia, 1u);
    uint ib = trash;
    ib = (hiB == rep[1][0]) ? (256u + loB) : ib;
    ib = (hiB == rep[1][1]) ? (512u + loB) : ib;
    ib = (hiB == rep[1][2]) ? (768u + loB) : ib;
    atomicAdd(hb + ib, 0x10000u);
  }
  __asm__ volatile("" ::: "memory");
  uint F1[3], F2[3], F3[3], SS2[3], CB2[3];
#pragma unroll
  for (int j = 0; j < 3; ++j)
    histpieces(hb + 256 + (j << 8), lane, F1[j], F2[j], F3[j], SS2[j], CB2[j]);
  float qv[2][3];
#pragma unroll
  for (int k = 0; k < 3; ++k) {
#pragma unroll
    for (int s = 0; s < 2; ++s) {
      int m = slt[s][k];
      uint f1 = (m == 0) ? F1[0] : (m == 1) ? F1[1] : F1[2];
      uint f2 = (m == 0) ? F2[0] : (m == 1) ? F2[1] : F2[2];
      uint f3 = (m == 0) ? F3[0] : (m == 1) ? F3[1] : F3[2];
      uint Sx = (m == 0) ? SS2[0] : (m == 1) ? SS2[1] : SS2[2];
      uint cx = (m == 0) ? CB2[0] : (m == 1) ? CB2[1] : CB2[2];
      uint lob, dummy;
      rankfind(r1[s][k], s << 4, f1, f2, f3, Sx, cx, lob, dummy);
      uint key = (b1[s][k] << 8) | lob;
      uint h = (key & 0x8000u) ? (key & 0x7FFFu) : (~key & 0xFFFFu);
      qv[s][k] = (float)u2h(h).x;
    }
  }

  // ---- patch sort-derived outputs into the stash (per wave, lane0) ----
  if (lane == 0) {
#pragma unroll
    for (int s = 0; s < 2; ++s) {
      int sh = s << 4;
      float mnf = (float)u2h(mnp >> sh).x;
      float mxf = (float)u2h(mxp >> sh).x;
      float* o = stash + ((wv << 1) + s) * 30;
      o[1]  = mnf;
      o[2]  = mxf;
      o[11] = qv[s][0];
      o[12] = qv[s][1];
      o[13] = qv[s][2];
      o[20] = fmaxf(fabsf(mnf), fabsf(mxf));
    }
  }
  __syncthreads();

  // ---- block-level epilogue: tid 0..7 -> one series each ----
  if (tid < 8) {
    const uint* rs = rawstash + (tid >> 1) * 20;
    const int sh = (tid & 1) << 4;
    float mean = (float)u2h(rs[0] >> sh).x;
    float s2   = (float)u2h(rs[1] >> sh).x;
    float s3   = (float)u2h(rs[2] >> sh).x;
    float s4   = (float)u2h(rs[3] >> sh).x;
    float sad  = (float)u2h(rs[4] >> sh).x;
    float sdd  = (float)u2h(rs[5] >> sh).x;
    float SD   = (float)u2h(rs[6] >> sh).x;
    float tb0  = (float)u2h(rs[7] >> sh).x;
    float tb1  = (float)u2h(rs[8] >> sh).x;
    float tb2  = (float)u2h(rs[9] >> sh).x;
    float tb3  = (float)u2h(rs[10] >> sh).x;
    float tb4  = (float)u2h(rs[11] >> sh).x;
    float fcpos = (float)((rs[12] >> sh) & 0xFFFF);
    float fcm   = (float)((rs[13] >> sh) & 0xFFFF);
    float fc0   = (float)((rs[14] >> sh) & 0xFFFF);
    float fc1   = (float)((rs[15] >> sh) & 0xFFFF);
    float fc2   = (float)((rs[16] >> sh) & 0xFFFF);
    float fc3   = (float)((rs[17] >> sh) & 0xFFFF);
    float fc4   = (float)((rs[18] >> sh) & 0xFFFF);

    float ex2 = s2 * (1.0f / 1024.0f);
    float rms = __builtin_amdgcn_sqrtf(fmaxf(ex2, 0.f));
    float var = fmaxf(ex2 - mean * mean, 0.f);
    float stdv = __builtin_amdgcn_sqrtf(var);
    float m2 = mean * mean;
    float m3c = s3 - 3.f * mean * s2 + 2048.f * m2 * mean;
    const float coef3 = (float)(1024.0 / (1023.0 * 1022.0));
    float den3 = stdv * stdv * stdv;
    float skew = (den3 > 0.f) ? coef3 * m3c * __builtin_amdgcn_rcpf(den3) : 0.f;
    float k4c = s4 - 4.f * mean * s3 + 6.f * m2 * s2 - 3072.f * m2 * m2;
    float s2c = s2 - 1024.f * m2;
    float k22 = s2c * s2c;
    const float alpha = (float)(1024.0 * 1025.0 * 1023.0 / (1022.0 * 1021.0));
    const float rightc = (float)(3.0 * 1023.0 * 1023.0 / (1022.0 * 1021.0));
    float kurt = (k22 > 0.f) ? alpha * k4c * __builtin_amdgcn_rcpf(k22) - rightc
                             : -rightc;

    float* o = stash + tid * 30;
    o[0] = mean;  o[3] = rms;  o[4] = var;  o[5] = stdv;
    o[6] = skew;  o[7] = kurt;
    o[8] = SD * (1.0f / 1022.0f);
    o[9] = SD;
    o[10] = sad * (1.0f / 1022.0f);
    o[14] = tb0;  o[15] = tb1; o[16] = tb2; o[17] = tb3; o[18] = tb4;
    o[19] = s2;
    o[21] = sad;
    o[22] = __builtin_amdgcn_sqrtf(fmaxf(sdd, 0.f));
    o[23] = fcpos; o[24] = fcm;
    o[25] = fc0;   o[26] = fc1; o[27] = fc2; o[28] = fc3; o[29] = fc4;
  }
  __syncthreads();

  // ---- coalesced block output: 8 rows x 30 floats = 960 B contiguous ----
  if (tid < 240) {
    size_t base = ((size_t)((b << 5) + (f8 << 3))) * 30;
    out[base + tid] = stash[tid];
  }
}

extern "C" void kernel_launch(void* const* d_in, const int* in_sizes, int n_in,
                              void* d_out, int out_size, void* d_ws, size_t ws_size,
                              hipStream_t stream) {
  const float* x = (const float*)d_in[0];
  float* out = (float*)d_out;
  hipLaunchKernelGGL(feat_fused, dim3(2048), dim3(256), 0, stream, x, out);
}

// Round 8
// 114.442 us; speedup vs baseline: 1.0404x; 1.0280x over previous
//
#include <hip/hip_runtime.h>

// ExtractTsFeatures fused, f16-packed end-to-end: x (512,1024,32) fp32 -> out (512,32,30) fp32.
// FINAL = R5 exactly (best graded: 115.6us; dispatch 48.7us on its container).
// Session ledger: R0 129.3 (bitonic-sort baseline) -> R5 115.6 (sort replaced
// by exact 2-level LDS histogram selection, -800 VALU slots/wave). Rejected by
// measurement: staging restructures (R1/R2/R3: occupancy up, wall flat/worse),
// ILP-doubling (R4: VGPR spill), phase reorder (R6), pass-2 dedupe (R7: noise-
// to-negative on graded). Structure is latency+issue-bound: ~27us VALU issue
// (invariant across all variants) + ~22us DS-chain latency at the 15-waves/CU
// occupancy cap forced by the 4KB/wave transpose-staging floor.

typedef _Float16 h2 __attribute__((ext_vector_type(2)));
typedef unsigned int uint;
typedef unsigned long long u64;

#define KML0 0x0000000000000001ull   // lane 0 only
#define KML63 0x8000000000000000ull  // lane 63 only

__device__ __forceinline__ uint h2u(h2 v) { return __builtin_bit_cast(uint, v); }
__device__ __forceinline__ h2   u2h(uint v) { return __builtin_bit_cast(h2, v); }
__device__ __forceinline__ uint pkrtz(float a, float b) {
  return __builtin_bit_cast(uint, __builtin_amdgcn_cvt_pkrtz(a, b));
}
// pinned packed min/max (guarantee v_pk_*_f16)
__device__ __forceinline__ uint pmin(uint a, uint b) {
  uint r; asm("v_pk_min_f16 %0, %1, %2" : "=v"(r) : "v"(a), "v"(b)); return r;
}
__device__ __forceinline__ uint pmax(uint a, uint b) {
  uint r; asm("v_pk_max_f16 %0, %1, %2" : "=v"(r) : "v"(a), "v"(b)); return r;
}
// pinned per-lane select: lanes with mask-bit 1 take b, else a
__device__ __forceinline__ uint csel(uint a, uint b, u64 km) {
  uint r;
  asm("v_cndmask_b32 %0, %1, %2, %3" : "=v"(r) : "v"(a), "v"(b), "s"(km));
  return r;
}

// xor-exchange on packed u32: DPP masks 1,2,8 (VALU); swizzle 4,16.
template <int MASK>
__device__ __forceinline__ uint exu(uint x) {
  static_assert(MASK == 1 || MASK == 2 || MASK == 4 || MASK == 8 || MASK == 16,
                "bad mask");
  if constexpr (MASK == 1)  return (uint)__builtin_amdgcn_update_dpp(0, (int)x, 0xB1, 0xF, 0xF, true);
  if constexpr (MASK == 2)  return (uint)__builtin_amdgcn_update_dpp(0, (int)x, 0x4E, 0xF, 0xF, true);
  if constexpr (MASK == 8)  return (uint)__builtin_amdgcn_update_dpp(0, (int)x, 0x128, 0xF, 0xF, true);  // row_ror:8
  if constexpr (MASK == 4)  return (uint)__builtin_amdgcn_ds_swizzle((int)x, 0x101F);
  if constexpr (MASK == 16) return (uint)__builtin_amdgcn_ds_swizzle((int)x, 0x401F);
  return x;
}

__device__ __forceinline__ uint bpermu(int addr, uint x) {
  return (uint)__builtin_amdgcn_ds_bpermute(addr, (int)x);
}
__device__ __forceinline__ uint irdl(uint v, int l) {
  return (uint)__builtin_amdgcn_readlane((int)v, l);
}

// packed f16 DPP tree sum (both series); result uniform via readlane 63.
__device__ __forceinline__ uint red_sum_pk(uint v) {
#define RSTEP(C) { uint t = (uint)__builtin_amdgcn_update_dpp(0, (int)v, C, 0xF, 0xF, true); \
                   v = h2u(u2h(v) + u2h(t)); }
  RSTEP(0x111) RSTEP(0x112) RSTEP(0x114) RSTEP(0x118) RSTEP(0x142) RSTEP(0x143)
#undef RSTEP
  return irdl(v, 63);
}

// inclusive 64-lane add-scan, packed u32 (halves independent; cums <= 1024
// so no cross-half carry). Classic GCN DPP scan: 4x row_shr + 2x row_bcast.
__device__ __forceinline__ uint iscan_pk(uint v) {
#define SSTEP(C, RM) { uint t = (uint)__builtin_amdgcn_update_dpp(0, (int)v, C, RM, 0xF, true); \
                       v += t; }
  SSTEP(0x111, 0xF) SSTEP(0x112, 0xF) SSTEP(0x114, 0xF) SSTEP(0x118, 0xF)
  SSTEP(0x142, 0xA) SSTEP(0x143, 0xC)
#undef SSTEP
  return v;
}

// load 4 bins/lane from a 256-bin packed histogram; in-lane exclusive
// prefixes + wave scan pieces.
__device__ __forceinline__ void histpieces(const uint* base, int lane,
                                           uint& e1, uint& e2, uint& e3,
                                           uint& S, uint& cumb) {
  uint4 bv = *(const uint4*)(base + (lane << 2));
  e1 = bv.x; e2 = e1 + bv.y; e3 = e2 + bv.z;
  uint tot = e3 + bv.w;
  S = iscan_pk(tot);
  cumb = S - tot;
}

// find bin containing 0-based rank R for series half sh (0 or 16).
// bucket = bin index (0..255), resid = rank within that bin.
__device__ __forceinline__ void rankfind(uint R, int sh, uint e1, uint e2,
                                         uint e3, uint S, uint cumb,
                                         uint& bucket, uint& resid) {
  uint Ss = (S >> sh) & 0xFFFFu;
  u64 m = __ballot(Ss > R);
  int L = (int)__builtin_ctzll(m);
  uint cb = (irdl(cumb, L) >> sh) & 0xFFFFu;
  uint f1 = (irdl(e1, L) >> sh) & 0xFFFFu;
  uint f2 = (irdl(e2, L) >> sh) & 0xFFFFu;
  uint f3 = (irdl(e3, L) >> sh) & 0xFFFFu;
  uint r0 = R - cb;
  uint j = (uint)(r0 >= f1) + (uint)(r0 >= f2) + (uint)(r0 >= f3);
  uint ej = (j == 0) ? 0u : (j == 1) ? f1 : (j == 2) ? f2 : f3;
  bucket = ((uint)L << 2) + j;
  resid = r0 - ej;
}

__global__ __launch_bounds__(256, 6) void feat_fused(const float* __restrict__ x,
                                                     float* __restrict__ out) {
  __shared__ __align__(16) uint sm[4 * 1024];  // 4 packed rows x 1024 = 16 KiB
  __shared__ uint rawstash[4 * 20];            // per-wave raw packed stats
  __shared__ float stash[8 * 30];              // per-block output stage (960 B)
  const int tid  = threadIdx.x;
  const int lane = tid & 63;
  const int wv   = tid >> 6;
  const int g    = blockIdx.x;
  const int b  = ((g & 7) << 6) + (g >> 5);   // XCD swizzle: siblings share L2
  const int f8 = (g >> 3) & 3;

  // ---- stage 8 series as 4 packed f16 rows ----
  const float4* xv = (const float4*)x;
  const int fq = tid & 1, t0 = tid >> 1;
  const size_t base4 = (size_t)b * 8192 + (size_t)((f8 << 1) + fq);
#pragma unroll
  for (int it = 0; it < 8; ++it) {
    int t = t0 + (it << 7);
    float4 v = xv[base4 + (size_t)t * 8];
    sm[((fq << 1) + 0) * 1024 + t] = pkrtz(v.x, v.y);
    sm[((fq << 1) + 1) * 1024 + t] = pkrtz(v.z, v.w);
  }
  __syncthreads();

  // packed series pair: lo = f8*8 + 2*wv, hi = +1
  uint p[16];
  {
    const uint* src = sm + (wv << 10);
#pragma unroll
    for (int q = 0; q < 4; ++q) {
      uint4 v = *(const uint4*)(src + (q << 8) + (lane << 2));
      p[q * 4 + 0] = v.x; p[q * 4 + 1] = v.y;
      p[q * 4 + 2] = v.z; p[q * 4 + 3] = v.w;
    }
  }

  const int addr_nx = ((lane + 1) & 63) << 2;
  const int addr63  = (lane ^ 63) << 2;
  const bool is63 = (lane == 63);

  // ============== packed per-series stats (both series at once) ===========
  // tb values at t = 0, 256, 512, 767, 1023 (packed, uniform)
  uint tb0p = irdl(p[0], 0);
  uint tb1p = irdl(p[4], 0);
  uint tb2p = irdl(p[8], 0);
  uint tb3p = irdl(p[11], 63);
  uint tb4p = irdl(p[15], 63);

  // raw moments, packed f16
  h2 s1h = {0, 0}, s2h = {0, 0}, s3h = {0, 0}, s4h = {0, 0};
#pragma unroll
  for (int r = 0; r < 16; ++r) {
    h2 v = u2h(p[r]);
    h2 v2 = v * v;
    s1h += v;
    s2h += v2;
    s3h += v2 * v;
    s4h += v2 * v2;
  }
  uint s1r = red_sum_pk(h2u(s1h));
  const _Float16 inv1024 = (_Float16)(1.0f / 1024.0f);
  h2 invv = {inv1024, inv1024};
  uint meanp = irdl(h2u(u2h(s1r) * invv), 0);

  // counts: 1 v_cmp_gt_f16 per series per reg; hi half via one lshr per reg
  const uint tb0hh = tb0p >> 16, tb1hh = tb1p >> 16, tb2hh = tb2p >> 16;
  const uint tb3hh = tb3p >> 16, tb4hh = tb4p >> 16, meanhh = meanp >> 16;
  int cposA = 0, cposB = 0, cmA = 0, cmB = 0;
  int c0A = 0, c0B = 0, c1A = 0, c1B = 0, c2A = 0, c2B = 0;
  int c3A = 0, c3B = 0, c4A = 0, c4B = 0;
#pragma unroll
  for (int r = 0; r < 16; ++r) {
    _Float16 a = u2h(p[r]).x;
    _Float16 bb = u2h(p[r] >> 16).x;
    cposA += __popcll(__ballot(a > (_Float16)0));
    cposB += __popcll(__ballot(bb > (_Float16)0));
    cmA += __popcll(__ballot(a > u2h(meanp).x));
    cmB += __popcll(__ballot(bb > u2h(meanhh).x));
    c0A += __popcll(__ballot(a > u2h(tb0p).x));
    c0B += __popcll(__ballot(bb > u2h(tb0hh).x));
    c1A += __popcll(__ballot(a > u2h(tb1p).x));
    c1B += __popcll(__ballot(bb > u2h(tb1hh).x));
    c2A += __popcll(__ballot(a > u2h(tb2p).x));
    c2B += __popcll(__ballot(bb > u2h(tb2hh).x));
    c3A += __popcll(__ballot(a > u2h(tb3p).x));
    c3B += __popcll(__ballot(bb > u2h(tb3hh).x));
    c4A += __popcll(__ballot(a > u2h(tb4p).x));
    c4B += __popcll(__ballot(bb > u2h(tb4hh).x));
  }

  // diffs d_t = x[t]-x[t+1], t in [1,1022], packed; sum telescopes.
  uint j1 = irdl(p[4], 0), j2 = irdl(p[8], 0), j3 = irdl(p[12], 0);
  h2 sadh = {0, 0}, sddh = {0, 0};
#pragma unroll
  for (int q = 0; q < 4; ++q) {
    uint nv = bpermu(addr_nx, p[q * 4]);
    if (q == 0) nv = is63 ? j1 : nv;
    if (q == 1) nv = is63 ? j2 : nv;
    if (q == 2) nv = is63 ? j3 : nv;
#pragma unroll
    for (int i = 0; i < 4; ++i) {
      uint xn = (i < 3) ? p[q * 4 + i + 1] : nv;
      uint dvu = h2u(u2h(p[q * 4 + i]) - u2h(xn));
      if (q == 0 && i == 0) dvu = csel(dvu, 0u, KML0);   // t=0 excluded
      if (q == 3 && i == 3) dvu = csel(dvu, 0u, KML63);  // t=1023 excluded
      h2 dv = u2h(dvu);
      sadh += u2h(dvu & 0x7FFF7FFFu);
      sddh += dv * dv;
    }
  }
  uint s2r = red_sum_pk(h2u(s2h));
  uint s3r = red_sum_pk(h2u(s3h));
  uint s4r = red_sum_pk(h2u(s4h));
  uint sadr = red_sum_pk(h2u(sadh));
  uint sddr = red_sum_pk(h2u(sddh));
  uint x1p = irdl(p[1], 0), x1023p = irdl(p[15], 63);
  uint SDp = irdl(h2u(u2h(x1p) - u2h(x1023p)), 0);

  if (lane == 0) {
    uint* rs = rawstash + wv * 20;
    rs[0] = meanp; rs[1] = s2r; rs[2] = s3r; rs[3] = s4r;
    rs[4] = sadr;  rs[5] = sddr; rs[6] = SDp;
    rs[7] = tb0p;  rs[8] = tb1p; rs[9] = tb2p; rs[10] = tb3p; rs[11] = tb4p;
    rs[12] = (uint)(cposA | (cposB << 16));
    rs[13] = (uint)(cmA | (cmB << 16));
    rs[14] = (uint)(c0A | (c0B << 16));
    rs[15] = (uint)(c1A | (c1B << 16));
    rs[16] = (uint)(c2A | (c2B << 16));
    rs[17] = (uint)(c3A | (c3B << 16));
    rs[18] = (uint)(c4A | (c4B << 16));
  }

  // ======== exact order statistics via 2-level LDS histogram ==============
  // wave-private 1024-word region = the staging row this wave alone consumed.
  uint* hb = sm + (wv << 10);

  // -- f16 min/max on original values (packed, full-wave reduction) --
  uint mnv = p[0], mxv = p[0];
#pragma unroll
  for (int r = 1; r < 16; ++r) { mnv = pmin(mnv, p[r]); mxv = pmax(mxv, p[r]); }
  mnv = pmin(mnv, exu<1>(mnv));  mxv = pmax(mxv, exu<1>(mxv));
  mnv = pmin(mnv, exu<2>(mnv));  mxv = pmax(mxv, exu<2>(mxv));
  mnv = pmin(mnv, exu<4>(mnv));  mxv = pmax(mxv, exu<4>(mxv));
  mnv = pmin(mnv, exu<8>(mnv));  mxv = pmax(mxv, exu<8>(mxv));
  mnv = pmin(mnv, exu<16>(mnv)); mxv = pmax(mxv, exu<16>(mxv));
  mnv = pmin(mnv, bpermu(addr63, mnv));   // cross 32-lane halves
  mxv = pmax(mxv, bpermu(addr63, mxv));
  uint mnp = irdl(mnv, 0), mxp = irdl(mxv, 0);

  // -- transform to order-isomorphic u16 keys, in place --
  // key = sign ? ~h : (h | 0x8000), per 16-bit half.
#pragma unroll
  for (int r = 0; r < 16; ++r) {
    uint sg = (p[r] >> 15) & 0x10001u;
    p[r] = p[r] ^ (sg * 0x7FFFu) ^ 0x80008000u;
  }

  // -- pass 1: 256-bin histogram of high key byte (A in lo16, B in hi16) --
  {
    uint4 zz; zz.x = 0u; zz.y = 0u; zz.z = 0u; zz.w = 0u;
    *(uint4*)(hb + (lane << 2)) = zz;
  }
  __asm__ volatile("" ::: "memory");
#pragma unroll
  for (int r = 0; r < 16; ++r) {
    atomicAdd(hb + ((p[r] >> 8) & 0xFFu), 1u);
    atomicAdd(hb + (p[r] >> 24), 0x10000u);
  }
  __asm__ volatile("" ::: "memory");
  uint e1, e2, e3, S, cumb;
  histpieces(hb, lane, e1, e2, e3, S, cumb);
  uint b1[2][3], r1[2][3];
#pragma unroll
  for (int s = 0; s < 2; ++s) {
#pragma unroll
    for (int k = 0; k < 3; ++k) {
      const uint R = (k == 0) ? 256u : (k == 1) ? 512u : 767u;
      rankfind(R, s << 4, e1, e2, e3, S, cumb, b1[s][k], r1[s][k]);
    }
  }

  // -- pass 2: per-rank 256-bin histograms of low key byte --
  {
    uint4 zz; zz.x = 0u; zz.y = 0u; zz.z = 0u; zz.w = 0u;
#pragma unroll
    for (int z = 0; z < 3; ++z)
      *(uint4*)(hb + 256 + (z << 8) + (lane << 2)) = zz;
  }
  __asm__ volatile("" ::: "memory");
  const uint trash = (uint)lane;   // pass-1 bins are dead; per-lane slots
#pragma unroll
  for (int r = 0; r < 16; ++r) {
    uint loA = p[r] & 0xFFu,         hiA = (p[r] >> 8) & 0xFFu;
    uint loB = (p[r] >> 16) & 0xFFu, hiB = p[r] >> 24;
#pragma unroll
    for (int k = 0; k < 3; ++k) {
      uint ia = (hiA == b1[0][k]) ? (256u + ((uint)k << 8) + loA) : trash;
      atomicAdd(hb + ia, 1u);
      uint ib = (hiB == b1[1][k]) ? (256u + ((uint)k << 8) + loB) : trash;
      atomicAdd(hb + ib, 0x10000u);
    }
  }
  __asm__ volatile("" ::: "memory");
  float qv[2][3];
#pragma unroll
  for (int k = 0; k < 3; ++k) {
    uint f1, f2, f3, S2, c2;
    histpieces(hb + 256 + (k << 8), lane, f1, f2, f3, S2, c2);
#pragma unroll
    for (int s = 0; s < 2; ++s) {
      uint lob, dummy;
      rankfind(r1[s][k], s << 4, f1, f2, f3, S2, c2, lob, dummy);
      uint key = (b1[s][k] << 8) | lob;
      uint h = (key & 0x8000u) ? (key & 0x7FFFu) : (~key & 0xFFFFu);
      qv[s][k] = (float)u2h(h).x;
    }
  }

  // ---- patch sort-derived outputs into the stash (per wave, lane0) ----
  if (lane == 0) {
#pragma unroll
    for (int s = 0; s < 2; ++s) {
      int sh = s << 4;
      float mnf = (float)u2h(mnp >> sh).x;
      float mxf = (float)u2h(mxp >> sh).x;
      float* o = stash + ((wv << 1) + s) * 30;
      o[1]  = mnf;
      o[2]  = mxf;
      o[11] = qv[s][0];
      o[12] = qv[s][1];
      o[13] = qv[s][2];
      o[20] = fmaxf(fabsf(mnf), fabsf(mxf));
    }
  }
  __syncthreads();

  // ---- block-level epilogue: tid 0..7 -> one series each ----
  if (tid < 8) {
    const uint* rs = rawstash + (tid >> 1) * 20;
    const int sh = (tid & 1) << 4;
    float mean = (float)u2h(rs[0] >> sh).x;
    float s2   = (float)u2h(rs[1] >> sh).x;
    float s3   = (float)u2h(rs[2] >> sh).x;
    float s4   = (float)u2h(rs[3] >> sh).x;
    float sad  = (float)u2h(rs[4] >> sh).x;
    float sdd  = (float)u2h(rs[5] >> sh).x;
    float SD   = (float)u2h(rs[6] >> sh).x;
    float tb0  = (float)u2h(rs[7] >> sh).x;
    float tb1  = (float)u2h(rs[8] >> sh).x;
    float tb2  = (float)u2h(rs[9] >> sh).x;
    float tb3  = (float)u2h(rs[10] >> sh).x;
    float tb4  = (float)u2h(rs[11] >> sh).x;
    float fcpos = (float)((rs[12] >> sh) & 0xFFFF);
    float fcm   = (float)((rs[13] >> sh) & 0xFFFF);
    float fc0   = (float)((rs[14] >> sh) & 0xFFFF);
    float fc1   = (float)((rs[15] >> sh) & 0xFFFF);
    float fc2   = (float)((rs[16] >> sh) & 0xFFFF);
    float fc3   = (float)((rs[17] >> sh) & 0xFFFF);
    float fc4   = (float)((rs[18] >> sh) & 0xFFFF);

    float ex2 = s2 * (1.0f / 1024.0f);
    float rms = __builtin_amdgcn_sqrtf(fmaxf(ex2, 0.f));
    float var = fmaxf(ex2 - mean * mean, 0.f);
    float stdv = __builtin_amdgcn_sqrtf(var);
    float m2 = mean * mean;
    float m3c = s3 - 3.f * mean * s2 + 2048.f * m2 * mean;
    const float coef3 = (float)(1024.0 / (1023.0 * 1022.0));
    float den3 = stdv * stdv * stdv;
    float skew = (den3 > 0.f) ? coef3 * m3c * __builtin_amdgcn_rcpf(den3) : 0.f;
    float k4c = s4 - 4.f * mean * s3 + 6.f * m2 * s2 - 3072.f * m2 * m2;
    float s2c = s2 - 1024.f * m2;
    float k22 = s2c * s2c;
    const float alpha = (float)(1024.0 * 1025.0 * 1023.0 / (1022.0 * 1021.0));
    const float rightc = (float)(3.0 * 1023.0 * 1023.0 / (1022.0 * 1021.0));
    float kurt = (k22 > 0.f) ? alpha * k4c * __builtin_amdgcn_rcpf(k22) - rightc
                             : -rightc;

    float* o = stash + tid * 30;
    o[0] = mean;  o[3] = rms;  o[4] = var;  o[5] = stdv;
    o[6] = skew;  o[7] = kurt;
    o[8] = SD * (1.0f / 1022.0f);
    o[9] = SD;
    o[10] = sad * (1.0f / 1022.0f);
    o[14] = tb0;  o[15] = tb1; o[16] = tb2; o[17] = tb3; o[18] = tb4;
    o[19] = s2;
    o[21] = sad;
    o[22] = __builtin_amdgcn_sqrtf(fmaxf(sdd, 0.f));
    o[23] = fcpos; o[24] = fcm;
    o[25] = fc0;   o[26] = fc1; o[27] = fc2; o[28] = fc3; o[29] = fc4;
  }
  __syncthreads();

  // ---- coalesced block output: 8 rows x 30 floats = 960 B contiguous ----
  if (tid < 240) {
    size_t base = ((size_t)((b << 5) + (f8 << 3))) * 30;
    out[base + tid] = stash[tid];
  }
}

extern "C" void kernel_launch(void* const* d_in, const int* in_sizes, int n_in,
                              void* d_out, int out_size, void* d_ws, size_t ws_size,
                              hipStream_t stream) {
  const float* x = (const float*)d_in[0];
  float* out = (float*)d_out;
  hipLaunchKernelGGL(feat_fused, dim3(2048), dim3(256), 0, stream, x, out);
}